// Round 13
// baseline (141.878 us; speedup 1.0000x reference)
//
#include <hip/hip_runtime.h>
#include <hip/hip_bf16.h>
#include <math.h>

#define IN_DIM 128
#define OUT_DIM 64
#define NEG_SLOPE 0.01f
#define NBUCK 1024         // bucket bins (dst>>6); 782 used
#define EPT 16             // edges per thread in part1 (4096 edges/block)
#define CAP 32             // slots per (block,bucket) cell (mean 5.2, P(>32)~1e-16)
#define SECAP 2048         // se[] capacity per tail block (mean 1023)

typedef __attribute__((ext_vector_type(8))) short bf8_t;   // 8 bf16 (4 VGPRs)
typedef __attribute__((ext_vector_type(4))) float f4_t;    // MFMA acc

__device__ __forceinline__ bf8_t pack8(float4 a, float4 b) {
    union { bf8_t v; __hip_bfloat162 h[4]; } u;
    u.h[0] = __float22bfloat162_rn(make_float2(a.x, a.y));
    u.h[1] = __float22bfloat162_rn(make_float2(a.z, a.w));
    u.h[2] = __float22bfloat162_rn(make_float2(b.x, b.y));
    u.h[3] = __float22bfloat162_rn(make_float2(b.z, b.w));
    return u.v;
}

// ---- K_front: blocks [0,NP1) = part1 (deterministic private slabs, ZERO global
//               atomics, no memset needed), blocks [NP1,..) = MFMA gemm.
// slab payload u22 = (src<<6) | (dst&63); bucket implied by the slab cell.
__global__ __launch_bounds__(256) void k_front(
    const int* __restrict__ src, const int* __restrict__ dst, int E,
    const float4* __restrict__ h4, const float4* __restrict__ W4,
    const float* __restrict__ Wattn,
    __hip_bfloat16* __restrict__ zb, float* __restrict__ s_l, float* __restrict__ s_r,
    unsigned* __restrict__ tmp,      // [NP1][NBUCK][CAP]
    int* __restrict__ cntg,          // [NP1][NBUCK] — every cell written
    int N, int NP1)
{
    __shared__ int cntA[NBUCK];
    const int t = threadIdx.x;
    const int bid = blockIdx.x;

    if (bid < NP1) {
        // ===== part1: single pass — LDS-atomic rank + immediate slab store =====
        const int base_e = bid * (256 * EPT);
        for (int b = t; b < NBUCK; b += 256) cntA[b] = 0;
        __syncthreads();

        const size_t slab0 = (size_t)bid * NBUCK;
        #pragma unroll
        for (int i = 0; i < EPT; i++) {
            int ei = base_e + i * 256 + t;
            if (ei < E) {
                int s = src[ei], d = dst[ei];
                int b = d >> 6;
                int r = atomicAdd(&cntA[b], 1);
                if (r < CAP)
                    tmp[(slab0 + b) * CAP + r] = ((unsigned)s << 6) | (unsigned)(d & 63);
            }
        }
        __syncthreads();

        for (int b = t; b < NBUCK; b += 256) {
            int c = cntA[b];
            cntg[slab0 + b] = (c < CAP) ? c : CAP;
        }
    } else {
        // ================= gemm: MFMA, 64 nodes per block =================
        const int lane = t & 63;
        const int wv   = t >> 6;
        const int col  = lane & 15, quad = lane >> 4;
        const int n0   = (bid - NP1) * 64 + wv * 16;
        if (n0 >= N) return;   // safe: no __syncthreads in this branch

        bf8_t bf[4][4];
        #pragma unroll
        for (int ns = 0; ns < 4; ns++) {
            const float4* wrow = W4 + (size_t)(ns * 16 + col) * (IN_DIM / 4);
            #pragma unroll
            for (int kb = 0; kb < 4; kb++) {
                float4 x = wrow[kb * 8 + quad * 2];
                float4 y = wrow[kb * 8 + quad * 2 + 1];
                bf[kb][ns] = pack8(x, y);
            }
        }

        const int  na = n0 + col;
        const bool nv = (na < N);
        const float4* hrow = h4 + (size_t)(nv ? na : 0) * (IN_DIM / 4);
        const float4 zero = make_float4(0.f, 0.f, 0.f, 0.f);

        f4_t acc[4];
        #pragma unroll
        for (int ns = 0; ns < 4; ns++) acc[ns] = (f4_t){0.f, 0.f, 0.f, 0.f};

        #pragma unroll
        for (int kb = 0; kb < 4; kb++) {
            float4 x = nv ? hrow[kb * 8 + quad * 2]     : zero;
            float4 y = nv ? hrow[kb * 8 + quad * 2 + 1] : zero;
            bf8_t a = pack8(x, y);
            #pragma unroll
            for (int ns = 0; ns < 4; ns++)
                acc[ns] = __builtin_amdgcn_mfma_f32_16x16x32_bf16(a, bf[kb][ns], acc[ns], 0, 0, 0);
        }

        float alv[4], arv[4];
        #pragma unroll
        for (int ns = 0; ns < 4; ns++) {
            alv[ns] = Wattn[ns * 16 + col];
            arv[ns] = Wattn[OUT_DIM + ns * 16 + col];
        }
        #pragma unroll
        for (int r = 0; r < 4; r++) {
            const int nn = n0 + quad * 4 + r;
            float pl = acc[0][r] * alv[0] + acc[1][r] * alv[1] + acc[2][r] * alv[2] + acc[3][r] * alv[3];
            float pr = acc[0][r] * arv[0] + acc[1][r] * arv[1] + acc[2][r] * arv[2] + acc[3][r] * arv[3];
            #pragma unroll
            for (int o = 1; o < 16; o <<= 1) {
                pl += __shfl_xor(pl, o, 64);
                pr += __shfl_xor(pr, o, 64);
            }
            if (nn < N) {
                __hip_bfloat16* zr = zb + (size_t)nn * OUT_DIM;
                #pragma unroll
                for (int ns = 0; ns < 4; ns++)
                    zr[ns * 16 + col] = __float2bfloat16(acc[ns][r]);
                if (col == 0) { s_l[nn] = pl; s_r[nn] = pr; }
            }
        }
    }
}

// ---- K_tail: one block per 64-node bucket.
// Phase 1: thread-per-fragment (NP1 fragments, each contiguous <=128B):
//   pass A: histogram dst&63 -> wave-0 shfl scan;
//   pass B: L1-hot re-read, compute ex, scatter {src,ex} to LDS.
// Phase 2: one 8-lane group per node; unroll-4 gather MLP; dsum in registers.
__global__ __launch_bounds__(256) void k_tail(
    const unsigned* __restrict__ tmp, const int* __restrict__ cntg,
    const float* __restrict__ s_l, const float* __restrict__ s_r,
    const uint4* __restrict__ zb4, float4* __restrict__ out4, int N, int NP1)
{
    __shared__ uint2 se[SECAP];              // 16 KB: {src, ex bits}
    __shared__ int cnt_s[64], off_s[64], cur_s[64];
    __shared__ float srs[64];

    const int b = blockIdx.x, t = threadIdx.x;
    const int lane = t & 63;
    const int nbase = b * 64;

    if (t < 64) {
        cnt_s[t] = 0;
        int n = nbase + t;
        srs[t] = (n < N) ? s_r[n] : 0.f;
    }
    __syncthreads();

    int myc = 0;
    size_t fbase = 0;
    if (t < NP1) {
        myc = cntg[(size_t)t * NBUCK + b];
        fbase = ((size_t)t * NBUCK + b) * CAP;
        for (int i = 0; i < myc; i++)
            atomicAdd(&cnt_s[tmp[fbase + i] & 63u], 1);
    }
    __syncthreads();

    // exclusive scan of cnt_s[64] by wave 0 (shfl only)
    if (t < 64) {
        int c = cnt_s[t];
        int inc = c;
        #pragma unroll
        for (int o = 1; o < 64; o <<= 1) {
            int v = __shfl_up(inc, o, 64);
            if (lane >= o) inc += v;
        }
        off_s[t] = inc - c;
        cur_s[t] = inc - c;
    }
    __syncthreads();

    // pass B: compute ex + scatter (fragment is L1-hot from pass A)
    if (t < NP1) {
        for (int i = 0; i < myc; i++) {
            unsigned p = tmp[fbase + i];
            int d = p & 63u;
            int s = p >> 6;
            float e = s_l[s] + srs[d];
            e = (e > 0.f) ? e : NEG_SLOPE * e;
            float ex = __expf(e);
            int slot = atomicAdd(&cur_s[d], 1);
            if (slot < SECAP)
                se[slot] = make_uint2((unsigned)s, __float_as_uint(ex));
        }
    }
    __syncthreads();

    // ---- phase 2: 8-lane group per node; no cross-lane ops ----
    const int ch8 = t & 7;       // which 16B chunk (8 bf16 channels) of the row
    const int grp = t >> 3;      // 0..31

    for (int nl = grp; nl < 64; nl += 32) {
        const int n = nbase + nl;
        if (n >= N) continue;
        const int beg = off_s[nl];
        int end = beg + cnt_s[nl];
        if (end > SECAP) end = SECAP;
        float4* op = out4 + (size_t)n * 16 + ch8 * 2;

        if (end <= beg) {
            op[0] = make_float4(0.f, 0.f, 0.f, 0.f);
            op[1] = make_float4(0.f, 0.f, 0.f, 0.f);
            continue;
        }

        float a0 = 0.f, a1 = 0.f, a2 = 0.f, a3 = 0.f;
        float a4 = 0.f, a5 = 0.f, a6 = 0.f, a7 = 0.f;
        float dsum = 0.f;

        #pragma unroll 4
        for (int i = beg; i < end; ++i) {
            uint2 q = se[i];              // ds_read_b64, broadcast within group
            float ex = __uint_as_float(q.y);
            dsum += ex;
            uint4 zv = zb4[(size_t)q.x * 8 + ch8];
            float f0 = __uint_as_float(zv.x << 16);
            float f1 = __uint_as_float(zv.x & 0xffff0000u);
            float f2 = __uint_as_float(zv.y << 16);
            float f3 = __uint_as_float(zv.y & 0xffff0000u);
            float f4 = __uint_as_float(zv.z << 16);
            float f5 = __uint_as_float(zv.z & 0xffff0000u);
            float f6 = __uint_as_float(zv.w << 16);
            float f7 = __uint_as_float(zv.w & 0xffff0000u);
            a0 += ex * f0; a1 += ex * f1; a2 += ex * f2; a3 += ex * f3;
            a4 += ex * f4; a5 += ex * f5; a6 += ex * f6; a7 += ex * f7;
        }

        float inv = 1.f / dsum;
        op[0] = make_float4(a0 * inv, a1 * inv, a2 * inv, a3 * inv);
        op[1] = make_float4(a4 * inv, a5 * inv, a6 * inv, a7 * inv);
    }
}

extern "C" void kernel_launch(void* const* d_in, const int* in_sizes, int n_in,
                              void* d_out, int out_size, void* d_ws, size_t ws_size,
                              hipStream_t stream)
{
    const float* h     = (const float*)d_in[0];
    const float* Wfc   = (const float*)d_in[1];
    const float* Wattn = (const float*)d_in[2];
    const int*   src   = (const int*)d_in[3];
    const int*   dst   = (const int*)d_in[4];
    const int N = in_sizes[0] / IN_DIM;
    const int E = in_sizes[3];
    const int NP1 = (E + 256 * EPT - 1) / (256 * EPT);  // 196 part1 blocks (<=256)
    const int NG  = (N + 63) / 64;                      // 782 buckets == gemm blocks

    // ws layout: z_bf16[N*64] | s_l[N] | s_r[N] | cntg[NP1*NBUCK] | tmp[NP1*NBUCK*CAP]
    __hip_bfloat16* zb = (__hip_bfloat16*)d_ws;
    float* s_l    = (float*)(zb + (size_t)N * OUT_DIM);
    float* s_r    = s_l + N;
    int*   cntg   = (int*)(s_r + N);
    unsigned* tmp = (unsigned*)(cntg + (size_t)NP1 * NBUCK);

    k_front<<<NP1 + NG, 256, 0, stream>>>(src, dst, E,
                                          (const float4*)h, (const float4*)Wfc, Wattn,
                                          zb, s_l, s_r, tmp, cntg, N, NP1);
    k_tail <<<NG, 256, 0, stream>>>(tmp, cntg, s_l, s_r,
                                    (const uint4*)zb, (float4*)d_out, N, NP1);
}

// Round 14
// 132.500 us; speedup vs baseline: 1.0708x; 1.0708x over previous
//
#include <hip/hip_runtime.h>
#include <hip/hip_bf16.h>
#include <math.h>

#define IN_DIM 128
#define OUT_DIM 64
#define NEG_SLOPE 0.01f
#define BCAP 2048          // slots per 64-node bucket (avg fill ~1023)
#define EPT 16             // edges per thread in part1 (4096 edges/block)

typedef __attribute__((ext_vector_type(8))) short bf8_t;   // 8 bf16 (4 VGPRs)
typedef __attribute__((ext_vector_type(4))) float f4_t;    // MFMA acc

__device__ __forceinline__ bf8_t pack8(float4 a, float4 b) {
    union { bf8_t v; __hip_bfloat162 h[4]; } u;
    u.h[0] = __float22bfloat162_rn(make_float2(a.x, a.y));
    u.h[1] = __float22bfloat162_rn(make_float2(a.z, a.w));
    u.h[2] = __float22bfloat162_rn(make_float2(b.x, b.y));
    u.h[3] = __float22bfloat162_rn(make_float2(b.z, b.w));
    return u.v;
}

// ---- K_front: blocks [0,NP1) = part1 (bin edges), blocks [NP1,..) = MFMA gemm ----
// payload u32 = (bucket<<22) | (src<<6) | (dst&63), bucket = dst>>6 (< 1024).
// Part1 uses ONE LDS-atomic pass: the histogram's return value is the edge's
// rank within (block,bucket); final scatter is gbase[b]+rank (no second atomic).
__global__ __launch_bounds__(256) void k_front(
    const int* __restrict__ src, const int* __restrict__ dst,
    int* __restrict__ bucket_cursor, unsigned* __restrict__ tmp, int E,
    const float4* __restrict__ h4, const float4* __restrict__ W4,
    const float* __restrict__ Wattn,
    __hip_bfloat16* __restrict__ zb, float* __restrict__ s_l, float* __restrict__ s_r,
    int N, int NP1)
{
    __shared__ int cntA[1024];
    __shared__ int gbase[1024];

    const int t = threadIdx.x;

    if (blockIdx.x < NP1) {
        // ================= part1: bin 4096 edges into buckets =================
        const int base_e = blockIdx.x * (256 * EPT);

        for (int b = t; b < 1024; b += 256) cntA[b] = 0;
        __syncthreads();

        unsigned pArr[EPT];
        unsigned short rArr[EPT];
        #pragma unroll
        for (int i = 0; i < EPT; i++) {
            int ei = base_e + i * 256 + t;
            if (ei < E) {
                int s = src[ei], d = dst[ei];
                int b = d >> 6;
                pArr[i] = ((unsigned)b << 22) | ((unsigned)s << 6) | (unsigned)(d & 63);
                rArr[i] = (unsigned short)atomicAdd(&cntA[b], 1);   // local rank
            } else {
                pArr[i] = 0xFFFFFFFFu;
            }
        }
        __syncthreads();

        for (int b = t; b < 1024; b += 256)
            if (cntA[b] > 0)
                gbase[b] = atomicAdd(&bucket_cursor[b], cntA[b]);
        __syncthreads();

        #pragma unroll
        for (int i = 0; i < EPT; i++) {
            unsigned p = pArr[i];
            if (p == 0xFFFFFFFFu) continue;
            int b = p >> 22;
            int slot = gbase[b] + rArr[i];
            if (slot < BCAP)
                tmp[(size_t)b * BCAP + slot] = p;
        }
    } else {
        // ================= gemm: MFMA, 64 nodes per block =================
        const int lane = t & 63;
        const int wv   = t >> 6;
        const int col  = lane & 15, quad = lane >> 4;
        const int n0   = (blockIdx.x - NP1) * 64 + wv * 16;
        if (n0 >= N) return;   // safe: no __syncthreads in this branch

        bf8_t bf[4][4];
        #pragma unroll
        for (int ns = 0; ns < 4; ns++) {
            const float4* wrow = W4 + (size_t)(ns * 16 + col) * (IN_DIM / 4);
            #pragma unroll
            for (int kb = 0; kb < 4; kb++) {
                float4 x = wrow[kb * 8 + quad * 2];
                float4 y = wrow[kb * 8 + quad * 2 + 1];
                bf[kb][ns] = pack8(x, y);
            }
        }

        const int  na = n0 + col;
        const bool nv = (na < N);
        const float4* hrow = h4 + (size_t)(nv ? na : 0) * (IN_DIM / 4);
        const float4 zero = make_float4(0.f, 0.f, 0.f, 0.f);

        f4_t acc[4];
        #pragma unroll
        for (int ns = 0; ns < 4; ns++) acc[ns] = (f4_t){0.f, 0.f, 0.f, 0.f};

        #pragma unroll
        for (int kb = 0; kb < 4; kb++) {
            float4 x = nv ? hrow[kb * 8 + quad * 2]     : zero;
            float4 y = nv ? hrow[kb * 8 + quad * 2 + 1] : zero;
            bf8_t a = pack8(x, y);
            #pragma unroll
            for (int ns = 0; ns < 4; ns++)
                acc[ns] = __builtin_amdgcn_mfma_f32_16x16x32_bf16(a, bf[kb][ns], acc[ns], 0, 0, 0);
        }

        float alv[4], arv[4];
        #pragma unroll
        for (int ns = 0; ns < 4; ns++) {
            alv[ns] = Wattn[ns * 16 + col];
            arv[ns] = Wattn[OUT_DIM + ns * 16 + col];
        }
        #pragma unroll
        for (int r = 0; r < 4; r++) {
            const int nn = n0 + quad * 4 + r;
            float pl = acc[0][r] * alv[0] + acc[1][r] * alv[1] + acc[2][r] * alv[2] + acc[3][r] * alv[3];
            float pr = acc[0][r] * arv[0] + acc[1][r] * arv[1] + acc[2][r] * arv[2] + acc[3][r] * arv[3];
            #pragma unroll
            for (int o = 1; o < 16; o <<= 1) {
                pl += __shfl_xor(pl, o, 64);
                pr += __shfl_xor(pr, o, 64);
            }
            if (nn < N) {
                __hip_bfloat16* zr = zb + (size_t)nn * OUT_DIM;
                #pragma unroll
                for (int ns = 0; ns < 4; ns++)
                    zr[ns * 16 + col] = __float2bfloat16(acc[ns][r]);
                if (col == 0) { s_l[nn] = pl; s_r[nn] = pr; }
            }
        }
    }
}

// ---- K_tail: one block per 64-node bucket.
// Phase 1 (single global pass): read slab once; compute ex; rank from the
// histogram atomic; stash (rank|src|d) + ex in LDS. After the wave-0 scan,
// pass B scatters LDS->LDS (no global re-read, no second expf).
// Phase 2: one 8-lane group per node; unroll-4 gather MLP; dsum in registers.
__global__ __launch_bounds__(256) void k_tail(
    const unsigned* __restrict__ tmp, const int* __restrict__ bucket_cnt,
    const float* __restrict__ s_l, const float* __restrict__ s_r,
    const uint4* __restrict__ zb4, float4* __restrict__ out4, int N)
{
    __shared__ uint2 se[BCAP];               // 16 KB: {src, ex bits}
    __shared__ unsigned p2s[BCAP];           // 8 KB: (rank<<22)|(src<<6)|d
    __shared__ float exs[BCAP];              // 8 KB
    __shared__ int cnt_s[64], off_s[64];
    __shared__ float srs[64];

    const int b = blockIdx.x, t = threadIdx.x;
    const int lane = t & 63;
    const int nbase = b * 64;
    int mb = bucket_cnt[b];
    if (mb > BCAP) mb = BCAP;

    if (t < 64) {
        cnt_s[t] = 0;
        int n = nbase + t;
        srs[t] = (n < N) ? s_r[n] : 0.f;
    }
    __syncthreads();

    const unsigned* mybuf = tmp + (size_t)b * BCAP;

    // pass A: single global read; histogram (rank) + ex, stashed in LDS
    for (int i = t; i < mb; i += 256) {
        unsigned p = mybuf[i];
        int d = p & 63u;
        int s = (p >> 6) & 0xFFFFu;
        float e = s_l[s] + srs[d];
        e = (e > 0.f) ? e : NEG_SLOPE * e;
        float ex = __expf(e);
        int r = atomicAdd(&cnt_s[d], 1);     // rank within node (max deg << 1024)
        if (r > 1023) r = 1023;
        p2s[i] = ((unsigned)r << 22) | (p & 0x3FFFFFu);
        exs[i] = ex;
    }
    __syncthreads();

    // exclusive scan of cnt_s[64] by wave 0 (shfl only)
    if (t < 64) {
        int c = cnt_s[t];
        int inc = c;
        #pragma unroll
        for (int o = 1; o < 64; o <<= 1) {
            int v = __shfl_up(inc, o, 64);
            if (lane >= o) inc += v;
        }
        off_s[t] = inc - c;
    }
    __syncthreads();

    // pass B: LDS -> LDS scatter into dst-sorted order
    for (int i = t; i < mb; i += 256) {
        unsigned q = p2s[i];
        int d = q & 63u;
        int slot = off_s[d] + (int)(q >> 22);
        if (slot < BCAP)
            se[slot] = make_uint2((q >> 6) & 0xFFFFu, __float_as_uint(exs[i]));
    }
    __syncthreads();

    // ---- phase 2: 8-lane group per node; no cross-lane ops ----
    const int ch8 = t & 7;       // which 16B chunk (8 bf16 channels) of the row
    const int grp = t >> 3;      // 0..31

    for (int nl = grp; nl < 64; nl += 32) {
        const int n = nbase + nl;
        if (n >= N) continue;
        const int beg = off_s[nl];
        int end = beg + cnt_s[nl];
        if (end > BCAP) end = BCAP;
        float4* op = out4 + (size_t)n * 16 + ch8 * 2;

        if (end <= beg) {
            op[0] = make_float4(0.f, 0.f, 0.f, 0.f);
            op[1] = make_float4(0.f, 0.f, 0.f, 0.f);
            continue;
        }

        float a0 = 0.f, a1 = 0.f, a2 = 0.f, a3 = 0.f;
        float a4 = 0.f, a5 = 0.f, a6 = 0.f, a7 = 0.f;
        float dsum = 0.f;

        #pragma unroll 4
        for (int i = beg; i < end; ++i) {
            uint2 q = se[i];              // ds_read_b64, broadcast within group
            float ex = __uint_as_float(q.y);
            dsum += ex;
            uint4 zv = zb4[(size_t)q.x * 8 + ch8];
            float f0 = __uint_as_float(zv.x << 16);
            float f1 = __uint_as_float(zv.x & 0xffff0000u);
            float f2 = __uint_as_float(zv.y << 16);
            float f3 = __uint_as_float(zv.y & 0xffff0000u);
            float f4 = __uint_as_float(zv.z << 16);
            float f5 = __uint_as_float(zv.z & 0xffff0000u);
            float f6 = __uint_as_float(zv.w << 16);
            float f7 = __uint_as_float(zv.w & 0xffff0000u);
            a0 += ex * f0; a1 += ex * f1; a2 += ex * f2; a3 += ex * f3;
            a4 += ex * f4; a5 += ex * f5; a6 += ex * f6; a7 += ex * f7;
        }

        float inv = 1.f / dsum;
        op[0] = make_float4(a0 * inv, a1 * inv, a2 * inv, a3 * inv);
        op[1] = make_float4(a4 * inv, a5 * inv, a6 * inv, a7 * inv);
    }
}

extern "C" void kernel_launch(void* const* d_in, const int* in_sizes, int n_in,
                              void* d_out, int out_size, void* d_ws, size_t ws_size,
                              hipStream_t stream)
{
    const float* h     = (const float*)d_in[0];
    const float* Wfc   = (const float*)d_in[1];
    const float* Wattn = (const float*)d_in[2];
    const int*   src   = (const int*)d_in[3];
    const int*   dst   = (const int*)d_in[4];
    const int N = in_sizes[0] / IN_DIM;
    const int E = in_sizes[3];
    const int NBK = (N + 63) / 64;                      // 782 buckets
    const int NP1 = (E + 256 * EPT - 1) / (256 * EPT);  // 196 part1 blocks

    // ws layout: z_bf16[N*64] | s_l[N] | s_r[N] | bucket_cursor[1024] | tmp[NBK*BCAP]
    __hip_bfloat16* zb = (__hip_bfloat16*)d_ws;
    float* s_l     = (float*)(zb + (size_t)N * OUT_DIM);
    float* s_r     = s_l + N;
    int*   bcursor = (int*)(s_r + N);
    unsigned* tmp  = (unsigned*)(bcursor + 1024);

    const int nblk_g = (N + 63) / 64;                   // 782 gemm blocks

    hipMemsetAsync(bcursor, 0, 1024 * sizeof(int), stream);

    k_front<<<NP1 + nblk_g, 256, 0, stream>>>(src, dst, bcursor, tmp, E,
                                              (const float4*)h, (const float4*)Wfc, Wattn,
                                              zb, s_l, s_r, N, NP1);
    k_tail <<<NBK, 256, 0, stream>>>(tmp, bcursor, s_l, s_r,
                                     (const uint4*)zb, (float4*)d_out, N);
}